// Round 1
// baseline (2186.414 us; speedup 1.0000x reference)
//
#include <hip/hip_runtime.h>
#include <cstdint>
#include <cstddef>
#include <cmath>

#define B_  4
#define H_  16
#define NT  512
#define NL  512
#define E_  64
#define P_  1024
#define HE  1024
#define BH  64

// ---------------------------------------------------------------------------
// Kernel A: per (b,n) precompute:
//   ibv  = 1/(exp(logvar)+8)
//   mobv = mu * ibv
//   bias = log(max(pi,tiny)) - 0.5*sum(mu^2*ibv) - 0.5*sum(log(bv))   (-inf if pi<=0)
// ---------------------------------------------------------------------------
__global__ __launch_bounds__(256) void k_precompute(
    const float* __restrict__ mu, const float* __restrict__ logvar,
    const float* __restrict__ pi, float* __restrict__ ibv,
    float* __restrict__ mobv, float* __restrict__ bias) {
  const int bn = blockIdx.x;          // 0 .. B_*NL-1
  const int t  = threadIdx.x;
  const size_t base = (size_t)bn * P_;
  float t2 = 0.f, t3 = 0.f;
#pragma unroll
  for (int i = 0; i < P_ / 256; ++i) {
    const int p = t + i * 256;
    const float lv  = logvar[base + p];
    const float v   = expf(lv);
    const float bv  = v + 8.0f;
    const float inv = 1.0f / bv;
    const float m   = mu[base + p];
    ibv[base + p]  = inv;
    mobv[base + p] = m * inv;
    t2 += m * m * inv;
    t3 += logf(bv);
  }
  __shared__ float r2[256];
  __shared__ float r3[256];
  r2[t] = t2; r3[t] = t3;
  __syncthreads();
  for (int s = 128; s > 0; s >>= 1) {
    if (t < s) { r2[t] += r2[t + s]; r3[t] += r3[t + s]; }
    __syncthreads();
  }
  if (t == 0) {
    const float pv = pi[bn];
    float bb;
    if (pv <= 0.f) bb = -INFINITY;
    else bb = logf(fmaxf(pv, 1.17549435e-38f)) - 0.5f * r2[0] - 0.5f * r3[0];
    bias[bn] = bb;
  }
}

// ---------------------------------------------------------------------------
// Kernel W: W2p[b][n][he] = 8 * sum_p mobv[b][n][p]*w_v[he][p] + b_v[he][n]
// GEMM C = A*B^T, A=mobv[b] [NL,P], B=w_v [HE,P]. 64x64 tile, 4x4 micro.
// ---------------------------------------------------------------------------
__global__ __launch_bounds__(256) void k_w2p(
    const float* __restrict__ mobv, const float* __restrict__ wv,
    const float* __restrict__ bv_, float* __restrict__ W2p) {
  const int b    = blockIdx.z;
  const int row0 = blockIdx.x * 64;   // n
  const int col0 = blockIdx.y * 64;   // he
  const float* A  = mobv + (size_t)b * NL * P_;
  __shared__ __align__(16) float As[32][68];
  __shared__ __align__(16) float Bs[32][68];
  const int t = threadIdx.x;
  const int tx = t & 15, ty = t >> 4;
  float acc[4][4];
#pragma unroll
  for (int i = 0; i < 4; ++i)
#pragma unroll
    for (int j = 0; j < 4; ++j) acc[i][j] = 0.f;

  for (int k0 = 0; k0 < P_; k0 += 32) {
#pragma unroll
    for (int i = 0; i < 2; ++i) {
      const int idx = t + i * 256;
      const int row = idx >> 3, k4 = (idx & 7) * 4;
      const float4 f = *(const float4*)&A[(size_t)(row0 + row) * P_ + k0 + k4];
      As[k4 + 0][row] = f.x; As[k4 + 1][row] = f.y;
      As[k4 + 2][row] = f.z; As[k4 + 3][row] = f.w;
      const float4 g = *(const float4*)&wv[(size_t)(col0 + row) * P_ + k0 + k4];
      Bs[k4 + 0][row] = g.x; Bs[k4 + 1][row] = g.y;
      Bs[k4 + 2][row] = g.z; Bs[k4 + 3][row] = g.w;
    }
    __syncthreads();
#pragma unroll
    for (int k = 0; k < 32; ++k) {
      const float4 a4 = *(const float4*)&As[k][ty * 4];
      const float4 b4 = *(const float4*)&Bs[k][tx * 4];
      const float av[4] = {a4.x, a4.y, a4.z, a4.w};
      const float bb[4] = {b4.x, b4.y, b4.z, b4.w};
#pragma unroll
      for (int i = 0; i < 4; ++i)
#pragma unroll
        for (int j = 0; j < 4; ++j) acc[i][j] += av[i] * bb[j];
    }
    __syncthreads();
  }
#pragma unroll
  for (int i = 0; i < 4; ++i) {
    const int n = row0 + ty * 4 + i;
    float o[4];
#pragma unroll
    for (int j = 0; j < 4; ++j) {
      const int he = col0 + tx * 4 + j;
      o[j] = 8.0f * acc[i][j] + bv_[(size_t)he * NL + n];
    }
    float4 o4; o4.x = o[0]; o4.y = o[1]; o4.z = o[2]; o4.w = o[3];
    *(float4*)&W2p[((size_t)b * NL + n) * HE + col0 + tx * 4] = o4;
  }
}

// ---------------------------------------------------------------------------
// Kernel S: scores[b][gr][n] = sum_p U[b][gr][p]*mobv[b][n][p] + pb + bias, mask
// ---------------------------------------------------------------------------
__global__ __launch_bounds__(256) void k_scores(
    const float* __restrict__ U, const float* __restrict__ mobv,
    const float* __restrict__ pb, const float* __restrict__ bias,
    const uint8_t* __restrict__ mask, float* __restrict__ attn) {
  const int b    = blockIdx.z;
  const int row0 = blockIdx.x * 64;   // gr within b (0..8191)
  const int col0 = blockIdx.y * 64;   // n
  const float* A  = U + (size_t)b * 8192 * P_;
  const float* Bm = mobv + (size_t)b * NL * P_;
  __shared__ __align__(16) float As[32][68];
  __shared__ __align__(16) float Bs[32][68];
  const int t = threadIdx.x;
  const int tx = t & 15, ty = t >> 4;
  float acc[4][4];
#pragma unroll
  for (int i = 0; i < 4; ++i)
#pragma unroll
    for (int j = 0; j < 4; ++j) acc[i][j] = 0.f;

  for (int k0 = 0; k0 < P_; k0 += 32) {
#pragma unroll
    for (int i = 0; i < 2; ++i) {
      const int idx = t + i * 256;
      const int row = idx >> 3, k4 = (idx & 7) * 4;
      const float4 f = *(const float4*)&A[(size_t)(row0 + row) * P_ + k0 + k4];
      As[k4 + 0][row] = f.x; As[k4 + 1][row] = f.y;
      As[k4 + 2][row] = f.z; As[k4 + 3][row] = f.w;
      const float4 g = *(const float4*)&Bm[(size_t)(col0 + row) * P_ + k0 + k4];
      Bs[k4 + 0][row] = g.x; Bs[k4 + 1][row] = g.y;
      Bs[k4 + 2][row] = g.z; Bs[k4 + 3][row] = g.w;
    }
    __syncthreads();
#pragma unroll
    for (int k = 0; k < 32; ++k) {
      const float4 a4 = *(const float4*)&As[k][ty * 4];
      const float4 b4 = *(const float4*)&Bs[k][tx * 4];
      const float av[4] = {a4.x, a4.y, a4.z, a4.w};
      const float bb[4] = {b4.x, b4.y, b4.z, b4.w};
#pragma unroll
      for (int i = 0; i < 4; ++i)
#pragma unroll
        for (int j = 0; j < 4; ++j) acc[i][j] += av[i] * bb[j];
    }
    __syncthreads();
  }
  const int bh = b * H_ + (row0 >> 9);   // 64-row tile never crosses an h boundary
#pragma unroll
  for (int i = 0; i < 4; ++i) {
    const int gr = row0 + ty * 4 + i;
    const float pbv = pb[(size_t)b * 8192 + gr];
    float o[4];
#pragma unroll
    for (int j = 0; j < 4; ++j) {
      const int n = col0 + tx * 4 + j;
      float s = acc[i][j] + pbv + bias[b * NL + n];
      if (mask[(size_t)bh * NL + n]) s = -INFINITY;
      o[j] = s;
    }
    float4 o4; o4.x = o[0]; o4.y = o[1]; o4.z = o[2]; o4.w = o[3];
    *(float4*)&attn[((size_t)b * 8192 + gr) * NL + col0 + tx * 4] = o4;
  }
}

// ---------------------------------------------------------------------------
// Kernel SM: softmax over last dim (512), in place. One block per row.
// ---------------------------------------------------------------------------
__global__ __launch_bounds__(256) void k_softmax(float* __restrict__ attn) {
  const size_t r = blockIdx.x;
  float* row = attn + r * NL;
  const int t = threadIdx.x;
  float2 v = ((float2*)row)[t];
  __shared__ float red[256];
  red[t] = fmaxf(v.x, v.y);
  __syncthreads();
  for (int s = 128; s > 0; s >>= 1) {
    if (t < s) red[t] = fmaxf(red[t], red[t + s]);
    __syncthreads();
  }
  const float M = red[0];
  __syncthreads();
  const float e0 = expf(v.x - M);
  const float e1 = expf(v.y - M);
  red[t] = e0 + e1;
  __syncthreads();
  for (int s = 128; s > 0; s >>= 1) {
    if (t < s) red[t] += red[t + s];
    __syncthreads();
  }
  const float inv = 1.0f / red[0];
  float2 o; o.x = e0 * inv; o.y = e1 * inv;
  ((float2*)row)[t] = o;
}

// ---------------------------------------------------------------------------
// Kernel O: fused output. Per block: one bh, 16 rows of Nt.
//   acc[m][e]  = sum_n A[m][n]*W2p[b][n][h*64+e]                (phase 1)
//             + sum_p (1-8*s1[m][p]) * u[m][p] * w_v[h][e][p]   (phase 2)
//   with s1 = A @ ibv, done in 16 chunks of 64 p.
// ---------------------------------------------------------------------------
__global__ __launch_bounds__(256) void k_out(
    const float* __restrict__ attn, const float* __restrict__ ibv,
    const float* __restrict__ W2p, const float* __restrict__ U,
    const float* __restrict__ wv, float* __restrict__ out) {
  const int mt = blockIdx.x;            // 0..31
  const int bh = blockIdx.y;            // 0..63
  const int b = bh >> 4, h = bh & 15;
  const int row0g = bh * NT + mt * 16;  // global row (B*H*Nt space)
  const int t = threadIdx.x;
  const int e  = t & 63;
  const int mg = t >> 6;                // 0..3; m = mg*4 + i

  __shared__ __align__(16) float a_mn[16][512];  // attn tile (32 KB)
  __shared__ __align__(16) float wvT[64][65];    // w_v chunk transposed
  __shared__ __align__(16) float opS[16][68];    // op chunk

  // stage attn tile, coalesced float4
#pragma unroll
  for (int i = 0; i < 8; ++i) {
    const int idx = t + i * 256;                 // 0..2047
    const int m = idx >> 7, n4 = (idx & 127) * 4;
    *(float4*)&a_mn[m][n4] =
        *(const float4*)&attn[(size_t)(row0g + m) * NL + n4];
  }
  __syncthreads();

  float acc[4] = {0.f, 0.f, 0.f, 0.f};

  // phase 1: term2 = A @ W2p[b,:,h*64+e]
  const float* W2r = W2p + (size_t)b * NL * HE + h * 64 + e;
  for (int n4 = 0; n4 < NL; n4 += 4) {
    const float w0 = W2r[(size_t)(n4 + 0) * HE];
    const float w1 = W2r[(size_t)(n4 + 1) * HE];
    const float w2 = W2r[(size_t)(n4 + 2) * HE];
    const float w3 = W2r[(size_t)(n4 + 3) * HE];
#pragma unroll
    for (int i = 0; i < 4; ++i) {
      const float4 a4 = *(const float4*)&a_mn[mg * 4 + i][n4];
      acc[i] += a4.x * w0 + a4.y * w1 + a4.z * w2 + a4.w * w3;
    }
  }

  // phase 2: 16 chunks of 64 p
  const float* ibv_b = ibv + (size_t)b * NL * P_;
  for (int c = 0; c < 16; ++c) {
    const int p0 = c * 64;
    __syncthreads();   // prev chunk's opS/wvT reads are done
    // stage wvT[pp][e'] = wv[h*64+e'][p0+pp]
#pragma unroll
    for (int i = 0; i < 4; ++i) {
      const int idx = t + i * 256;               // 0..1023
      const int ee = idx >> 4, p4 = (idx & 15) * 4;
      const float4 f =
          *(const float4*)&wv[(size_t)(h * 64 + ee) * P_ + p0 + p4];
      wvT[p4 + 0][ee] = f.x; wvT[p4 + 1][ee] = f.y;
      wvT[p4 + 2][ee] = f.z; wvT[p4 + 3][ee] = f.w;
    }
    // s1[i] = sum_n A[m][n] * ibv[n][p0+e]
    float s1[4] = {0.f, 0.f, 0.f, 0.f};
    const float* ibp = ibv_b + p0 + e;
    for (int n4 = 0; n4 < NL; n4 += 4) {
      const float v0 = ibp[(size_t)(n4 + 0) * P_];
      const float v1 = ibp[(size_t)(n4 + 1) * P_];
      const float v2 = ibp[(size_t)(n4 + 2) * P_];
      const float v3 = ibp[(size_t)(n4 + 3) * P_];
#pragma unroll
      for (int i = 0; i < 4; ++i) {
        const float4 a4 = *(const float4*)&a_mn[mg * 4 + i][n4];
        s1[i] += a4.x * v0 + a4.y * v1 + a4.z * v2 + a4.w * v3;
      }
    }
    // op = (1 - 8*s1) * u
#pragma unroll
    for (int i = 0; i < 4; ++i) {
      const int m = mg * 4 + i;
      const float uu = U[(size_t)(row0g + m) * P_ + p0 + e];
      opS[m][e] = (1.0f - 8.0f * s1[i]) * uu;
    }
    __syncthreads();
    // projection: acc[i] += sum_pp opS[m][pp] * wvT[pp][e]
#pragma unroll
    for (int q = 0; q < 16; ++q) {
      const float w0 = wvT[q * 4 + 0][e];
      const float w1 = wvT[q * 4 + 1][e];
      const float w2 = wvT[q * 4 + 2][e];
      const float w3 = wvT[q * 4 + 3][e];
#pragma unroll
      for (int i = 0; i < 4; ++i) {
        const float4 o4 = *(const float4*)&opS[mg * 4 + i][q * 4];
        acc[i] += o4.x * w0 + o4.y * w1 + o4.z * w2 + o4.w * w3;
      }
    }
  }
#pragma unroll
  for (int i = 0; i < 4; ++i) {
    out[(size_t)(row0g + mg * 4 + i) * E_ + e] = acc[i];
  }
}

// ---------------------------------------------------------------------------
extern "C" void kernel_launch(void* const* d_in, const int* in_sizes, int n_in,
                              void* d_out, int out_size, void* d_ws, size_t ws_size,
                              hipStream_t stream) {
  const float*   u    = (const float*)d_in[0];   // [B,H,Nt,P]
  const float*   pb   = (const float*)d_in[1];   // [B,H,Nt,1]
  const float*   mu   = (const float*)d_in[2];   // [B,Nl,P]
  const float*   logv = (const float*)d_in[3];   // [B,Nl,P]
  const float*   pi   = (const float*)d_in[4];   // [B,Nl,1]
  const float*   wv   = (const float*)d_in[5];   // [H,E,P]
  const float*   bv   = (const float*)d_in[6];   // [H,E,Nl]
  const uint8_t* mask = (const uint8_t*)d_in[7]; // [B*H,1,Nl] bool

  float* out  = (float*)d_out;                      // [B*H,Nt,E]
  float* attn = out + (size_t)BH * NT * E_;         // [B*H,Nt,Nl]

  float* ws   = (float*)d_ws;
  float* ibv  = ws;                                 // B*NL*P
  float* mobv = ibv  + (size_t)B_ * NL * P_;        // B*NL*P
  float* W2p  = mobv + (size_t)B_ * NL * P_;        // B*NL*HE
  float* bias = W2p  + (size_t)B_ * NL * HE;        // B*NL

  k_precompute<<<B_ * NL, 256, 0, stream>>>(mu, logv, pi, ibv, mobv, bias);
  k_w2p<<<dim3(NL / 64, HE / 64, B_), 256, 0, stream>>>(mobv, wv, bv, W2p);
  k_scores<<<dim3(8192 / 64, NL / 64, B_), 256, 0, stream>>>(u, mobv, pb, bias,
                                                             mask, attn);
  k_softmax<<<B_ * H_ * NT, 256, 0, stream>>>(attn);
  k_out<<<dim3(NT / 16, BH), 256, 0, stream>>>(attn, ibv, W2p, u, wv, out);
}

// Round 2
// 1149.039 us; speedup vs baseline: 1.9028x; 1.9028x over previous
//
#include <hip/hip_runtime.h>
#include <cstdint>
#include <cstddef>
#include <cmath>

#define B_  4
#define H_  16
#define NT  512
#define NL  512
#define E_  64
#define P_  1024
#define HE  1024
#define BH  64

typedef __attribute__((ext_vector_type(8))) short short8;
typedef __attribute__((ext_vector_type(4))) float f32x4;
typedef unsigned short u16;

#define MFMA(a, b, c) __builtin_amdgcn_mfma_f32_16x16x32_bf16(a, b, c, 0, 0, 0)

static __device__ inline u16 f2bf_rne(float f) {
  unsigned u = __float_as_uint(f);
  unsigned r = u + 0x7FFFu + ((u >> 16) & 1u);
  return (u16)(r >> 16);
}

// ---------------------------------------------------------------------------
// Kernel A: per (b,n):
//   inv = 1/(exp(logvar)+8); mobv = mu*inv (fp32 + hi/lo bf16 split);
//   ibvT[b][p][n] = bf16(inv)  (transposed for MFMA B-fragments);
//   bias = log(pi) - 0.5*sum(mu^2*inv) - 0.5*sum(log(bv))
// ---------------------------------------------------------------------------
__global__ __launch_bounds__(256) void k_precompute(
    const float* __restrict__ mu, const float* __restrict__ logvar,
    const float* __restrict__ pi, float* __restrict__ mobv,
    u16* __restrict__ mobv_hi, u16* __restrict__ mobv_lo,
    u16* __restrict__ ibvT, float* __restrict__ bias) {
  const int bn = blockIdx.x;          // 0 .. B_*NL-1
  const int b = bn >> 9, n = bn & 511;
  const int t = threadIdx.x;
  const size_t base = (size_t)bn * P_;
  float t2 = 0.f, t3 = 0.f;
#pragma unroll
  for (int i = 0; i < P_ / 256; ++i) {
    const int p = t + i * 256;
    const float lv  = logvar[base + p];
    const float v   = expf(lv);
    const float bv  = v + 8.0f;
    const float inv = 1.0f / bv;
    const float m   = mu[base + p];
    const float x   = m * inv;
    mobv[base + p] = x;
    const unsigned bits = __float_as_uint(x);
    mobv_hi[base + p] = (u16)(bits >> 16);
    const float r = x - __uint_as_float(bits & 0xFFFF0000u);
    mobv_lo[base + p] = (u16)(__float_as_uint(r) >> 16);
    ibvT[((size_t)b * P_ + p) * NL + n] = f2bf_rne(inv);
    t2 += m * x;
    t3 += logf(bv);
  }
  __shared__ float r2[256];
  __shared__ float r3[256];
  r2[t] = t2; r3[t] = t3;
  __syncthreads();
  for (int s = 128; s > 0; s >>= 1) {
    if (t < s) { r2[t] += r2[t + s]; r3[t] += r3[t + s]; }
    __syncthreads();
  }
  if (t == 0) {
    const float pv = pi[bn];
    float bb;
    if (pv <= 0.f) bb = -INFINITY;
    else bb = logf(fmaxf(pv, 1.17549435e-38f)) - 0.5f * r2[0] - 0.5f * r3[0];
    bias[bn] = bb;
  }
}

// ---------------------------------------------------------------------------
// wv fp32 -> bf16 copy (B-fragment source for the projection GEMM)
// ---------------------------------------------------------------------------
__global__ __launch_bounds__(256) void k_wvcast(const float* __restrict__ wv,
                                                u16* __restrict__ wvb) {
  const int i = (blockIdx.x * 256 + threadIdx.x) * 4;
  const float4 f = *(const float4*)&wv[i];
  wvb[i + 0] = f2bf_rne(f.x);
  wvb[i + 1] = f2bf_rne(f.y);
  wvb[i + 2] = f2bf_rne(f.z);
  wvb[i + 3] = f2bf_rne(f.w);
}

// ---------------------------------------------------------------------------
// Kernel W: W2pT[b][he][n] = bf16( 8*sum_p mobv[b][n][p]*w_v[he][p] + b_v[he][n] )
// fp32 GEMM (small: 4.3 GF), transposed bf16 output for term2 B-fragments.
// ---------------------------------------------------------------------------
__global__ __launch_bounds__(256) void k_w2p(
    const float* __restrict__ mobv, const float* __restrict__ wv,
    const float* __restrict__ bv_, u16* __restrict__ W2pT) {
  const int b    = blockIdx.z;
  const int row0 = blockIdx.x * 64;   // n
  const int col0 = blockIdx.y * 64;   // he
  const float* A  = mobv + (size_t)b * NL * P_;
  __shared__ __align__(16) float As[32][68];
  __shared__ __align__(16) float Bs[32][68];
  const int t = threadIdx.x;
  const int tx = t & 15, ty = t >> 4;
  float acc[4][4];
#pragma unroll
  for (int i = 0; i < 4; ++i)
#pragma unroll
    for (int j = 0; j < 4; ++j) acc[i][j] = 0.f;

  for (int k0 = 0; k0 < P_; k0 += 32) {
#pragma unroll
    for (int i = 0; i < 2; ++i) {
      const int idx = t + i * 256;
      const int row = idx >> 3, k4 = (idx & 7) * 4;
      const float4 f = *(const float4*)&A[(size_t)(row0 + row) * P_ + k0 + k4];
      As[k4 + 0][row] = f.x; As[k4 + 1][row] = f.y;
      As[k4 + 2][row] = f.z; As[k4 + 3][row] = f.w;
      const float4 g = *(const float4*)&wv[(size_t)(col0 + row) * P_ + k0 + k4];
      Bs[k4 + 0][row] = g.x; Bs[k4 + 1][row] = g.y;
      Bs[k4 + 2][row] = g.z; Bs[k4 + 3][row] = g.w;
    }
    __syncthreads();
#pragma unroll
    for (int k = 0; k < 32; ++k) {
      const float4 a4 = *(const float4*)&As[k][ty * 4];
      const float4 b4 = *(const float4*)&Bs[k][tx * 4];
      const float av[4] = {a4.x, a4.y, a4.z, a4.w};
      const float bb[4] = {b4.x, b4.y, b4.z, b4.w};
#pragma unroll
      for (int i = 0; i < 4; ++i)
#pragma unroll
        for (int j = 0; j < 4; ++j) acc[i][j] += av[i] * bb[j];
    }
    __syncthreads();
  }
#pragma unroll
  for (int i = 0; i < 4; ++i) {
    const int n = row0 + ty * 4 + i;
#pragma unroll
    for (int j = 0; j < 4; ++j) {
      const int he = col0 + tx * 4 + j;
      const float o = 8.0f * acc[i][j] + bv_[(size_t)he * NL + n];
      W2pT[((size_t)b * HE + he) * NL + n] = f2bf_rne(o);
    }
  }
}

// ---------------------------------------------------------------------------
// Kernel S (MFMA): scores = U @ mobv^T with split-bf16 (hi/lo) accuracy.
// Block: 64 rows (gr) x 64 cols (n); 4 waves, wave owns 16 rows x 64 cols.
// A-frags direct from global fp32 U (split in-register); B-frags direct
// from global bf16 mobv_hi/lo (k-contiguous).
// ---------------------------------------------------------------------------
__global__ __launch_bounds__(256) void k_scores(
    const float* __restrict__ U, const u16* __restrict__ mobv_hi,
    const u16* __restrict__ mobv_lo, const float* __restrict__ pb,
    const float* __restrict__ bias, const uint8_t* __restrict__ mask,
    float* __restrict__ attn) {
  const int b    = blockIdx.z;
  const int row0 = blockIdx.x * 64;   // gr within b
  const int col0 = blockIdx.y * 64;   // n
  const int t = threadIdx.x;
  const int wave = t >> 6, lane = t & 63;
  const int l16 = lane & 15, sel = lane >> 4;
  const int wm = wave * 16;

  f32x4 acc[4];
#pragma unroll
  for (int i = 0; i < 4; ++i) acc[i] = (f32x4){0.f, 0.f, 0.f, 0.f};

  const float* Urow = U + ((size_t)b * 8192 + row0 + wm + l16) * P_;
  const size_t bnp = (size_t)b * NL * P_;

  for (int ks = 0; ks < 32; ++ks) {
    const int k = ks * 32 + sel * 8;
    const float4 f0 = *(const float4*)&Urow[k];
    const float4 f1 = *(const float4*)&Urow[k + 4];
    const float fv[8] = {f0.x, f0.y, f0.z, f0.w, f1.x, f1.y, f1.z, f1.w};
    short8 ah, al;
#pragma unroll
    for (int j = 0; j < 8; ++j) {
      const unsigned bits = __float_as_uint(fv[j]);
      ah[j] = (short)(bits >> 16);
      const float r = fv[j] - __uint_as_float(bits & 0xFFFF0000u);
      al[j] = (short)(__float_as_uint(r) >> 16);
    }
#pragma unroll
    for (int nt = 0; nt < 4; ++nt) {
      const int n = col0 + nt * 16 + l16;
      const short8 bh = *(const short8*)(mobv_hi + bnp + (size_t)n * P_ + k);
      const short8 bl = *(const short8*)(mobv_lo + bnp + (size_t)n * P_ + k);
      acc[nt] = MFMA(ah, bh, acc[nt]);
      acc[nt] = MFMA(ah, bl, acc[nt]);
      acc[nt] = MFMA(al, bh, acc[nt]);
    }
  }
  const int bh_ = b * H_ + (row0 >> 9);
#pragma unroll
  for (int nt = 0; nt < 4; ++nt) {
    const int n = col0 + nt * 16 + l16;
    const float bcol = bias[b * NL + n];
    const bool mk = mask[(size_t)bh_ * NL + n] != 0;
#pragma unroll
    for (int r = 0; r < 4; ++r) {
      const int row = row0 + wm + sel * 4 + r;
      float s = acc[nt][r] + pb[(size_t)b * 8192 + row] + bcol;
      if (mk) s = -INFINITY;
      attn[((size_t)b * 8192 + row) * NL + n] = s;
    }
  }
}

// ---------------------------------------------------------------------------
// Kernel SM: softmax over last dim (512), in place. One block per row.
// ---------------------------------------------------------------------------
__global__ __launch_bounds__(256) void k_softmax(float* __restrict__ attn) {
  const size_t r = blockIdx.x;
  float* row = attn + r * NL;
  const int t = threadIdx.x;
  float2 v = ((float2*)row)[t];
  __shared__ float red[256];
  red[t] = fmaxf(v.x, v.y);
  __syncthreads();
  for (int s = 128; s > 0; s >>= 1) {
    if (t < s) red[t] = fmaxf(red[t], red[t + s]);
    __syncthreads();
  }
  const float M = red[0];
  __syncthreads();
  const float e0 = expf(v.x - M);
  const float e1 = expf(v.y - M);
  red[t] = e0 + e1;
  __syncthreads();
  for (int s = 128; s > 0; s >>= 1) {
    if (t < s) red[t] += red[t + s];
    __syncthreads();
  }
  const float inv = 1.0f / red[0];
  float2 o; o.x = e0 * inv; o.y = e1 * inv;
  ((float2*)row)[t] = o;
}

// ---------------------------------------------------------------------------
// Kernel O (MFMA): fused output. Block: one bh, 32 rows of Nt; 4 waves.
//   acc[32m][64e] = A @ W2pT^T  (term2, k=512 over n)
//                 + sum over 16 p-chunks: op_chunk @ wv^T
//   op = (1 - 8*(A @ ibvT^T)) * u, bf16 round-trip through LDS for the
//   C-layout -> A-layout transform (flash-attention pattern).
// Wave w: out tile rows mh=(w&1)*16, cols eh=(w>>1)*32; s1 tile rows mh,
// p-range ph=(w>>1)*32.
// ---------------------------------------------------------------------------
__global__ __launch_bounds__(256) void k_out(
    const float* __restrict__ attn, const u16* __restrict__ ibvT,
    const u16* __restrict__ W2pT, const float* __restrict__ U,
    const u16* __restrict__ wvb, float* __restrict__ out) {
  const int bh = blockIdx.y;
  const int b = bh >> 4, h = bh & 15;
  const int row0g = bh * NT + blockIdx.x * 32;
  const int t = threadIdx.x;
  const int wave = t >> 6, lane = t & 63;
  const int l16 = lane & 15, sel = lane >> 4;
  const int mh = (wave & 1) * 16;
  const int eh = (wave >> 1) * 32;
  const int ph = (wave >> 1) * 32;

  __shared__ u16 As[32][520];   // attn tile bf16 (row stride 1040B: 2-way-free banks)
  __shared__ u16 opS[32][72];   // op chunk bf16

  // stage attn (fp32 global -> bf16 LDS), coalesced float4
#pragma unroll
  for (int i = 0; i < 16; ++i) {
    const int idx = t + i * 256;       // 0..4095
    const int row = idx >> 7;
    const int c4 = (idx & 127) * 4;
    const float4 f = *(const float4*)&attn[(size_t)(row0g + row) * NL + c4];
    As[row][c4 + 0] = f2bf_rne(f.x);
    As[row][c4 + 1] = f2bf_rne(f.y);
    As[row][c4 + 2] = f2bf_rne(f.z);
    As[row][c4 + 3] = f2bf_rne(f.w);
  }
  __syncthreads();

  f32x4 acc0 = (f32x4){0.f, 0.f, 0.f, 0.f};
  f32x4 acc1 = (f32x4){0.f, 0.f, 0.f, 0.f};

  // term2: acc += A @ W2pT^T   (k = n, 512)
#pragma unroll 4
  for (int ks = 0; ks < 16; ++ks) {
    const short8 a = *(const short8*)&As[mh + l16][ks * 32 + sel * 8];
    const int he0 = h * 64 + eh + l16;
    const short8 b0 =
        *(const short8*)&W2pT[((size_t)b * HE + he0) * NL + ks * 32 + sel * 8];
    acc0 = MFMA(a, b0, acc0);
    const short8 b1 = *(const short8*)&W2pT[((size_t)b * HE + he0 + 16) * NL +
                                            ks * 32 + sel * 8];
    acc1 = MFMA(a, b1, acc1);
  }

  // p-chunk loop
  for (int c = 0; c < 16; ++c) {
    const int p0 = c * 64;
    f32x4 s0 = (f32x4){0.f, 0.f, 0.f, 0.f};
    f32x4 s1 = (f32x4){0.f, 0.f, 0.f, 0.f};
#pragma unroll 4
    for (int ks = 0; ks < 16; ++ks) {
      const short8 a = *(const short8*)&As[mh + l16][ks * 32 + sel * 8];
      const int pc = p0 + ph + l16;
      const short8 b0 =
          *(const short8*)&ibvT[((size_t)b * P_ + pc) * NL + ks * 32 + sel * 8];
      s0 = MFMA(a, b0, s0);
      const short8 b1 = *(const short8*)&ibvT[((size_t)b * P_ + pc + 16) * NL +
                                              ks * 32 + sel * 8];
      s1 = MFMA(a, b1, s1);
    }
    // op = (1 - 8*s1)*u, C-layout -> LDS (bf16)
#pragma unroll
    for (int r = 0; r < 4; ++r) {
      const int row = mh + sel * 4 + r;
      const float u0 = U[(size_t)(row0g + row) * P_ + p0 + ph + l16];
      const float u1 = U[(size_t)(row0g + row) * P_ + p0 + ph + 16 + l16];
      opS[row][ph + l16]      = f2bf_rne((1.0f - 8.0f * s0[r]) * u0);
      opS[row][ph + 16 + l16] = f2bf_rne((1.0f - 8.0f * s1[r]) * u1);
    }
    __syncthreads();
    // projection: acc += op @ wv^T   (k = p, 64)
#pragma unroll
    for (int ks = 0; ks < 2; ++ks) {
      const short8 a = *(const short8*)&opS[mh + l16][ks * 32 + sel * 8];
      const int he0 = h * 64 + eh + l16;
      const short8 b0 =
          *(const short8*)&wvb[(size_t)he0 * P_ + p0 + ks * 32 + sel * 8];
      acc0 = MFMA(a, b0, acc0);
      const short8 b1 = *(const short8*)&wvb[(size_t)(he0 + 16) * P_ + p0 +
                                             ks * 32 + sel * 8];
      acc1 = MFMA(a, b1, acc1);
    }
    __syncthreads();
  }
#pragma unroll
  for (int r = 0; r < 4; ++r) {
    const int row = mh + sel * 4 + r;
    out[(size_t)(row0g + row) * E_ + eh + l16]      = acc0[r];
    out[(size_t)(row0g + row) * E_ + eh + 16 + l16] = acc1[r];
  }
}

// ---------------------------------------------------------------------------
extern "C" void kernel_launch(void* const* d_in, const int* in_sizes, int n_in,
                              void* d_out, int out_size, void* d_ws, size_t ws_size,
                              hipStream_t stream) {
  const float*   u    = (const float*)d_in[0];   // [B,H,Nt,P]
  const float*   pb   = (const float*)d_in[1];   // [B,H,Nt,1]
  const float*   mu   = (const float*)d_in[2];   // [B,Nl,P]
  const float*   logv = (const float*)d_in[3];   // [B,Nl,P]
  const float*   pi   = (const float*)d_in[4];   // [B,Nl,1]
  const float*   wv   = (const float*)d_in[5];   // [H,E,P]
  const float*   bv   = (const float*)d_in[6];   // [H,E,Nl]
  const uint8_t* mask = (const uint8_t*)d_in[7]; // [B*H,1,Nl] bool

  float* out  = (float*)d_out;                      // [B*H,Nt,E]
  float* attn = out + (size_t)BH * NT * E_;         // [B*H,Nt,Nl]

  float* mobv    = (float*)d_ws;                            // B*NL*P fp32 (8 MB)
  u16*   mobv_hi = (u16*)(mobv + (size_t)B_ * NL * P_);     // 4 MB
  u16*   mobv_lo = mobv_hi + (size_t)B_ * NL * P_;          // 4 MB
  u16*   ibvT    = mobv_lo + (size_t)B_ * NL * P_;          // [b][p][n] 4 MB
  u16*   W2pT    = ibvT + (size_t)B_ * P_ * NL;             // [b][he][n] 4 MB
  u16*   wvb     = W2pT + (size_t)B_ * HE * NL;             // [he][p] 2 MB
  float* bias    = (float*)(wvb + (size_t)HE * P_);         // B*NL

  k_precompute<<<B_ * NL, 256, 0, stream>>>(mu, logv, pi, mobv, mobv_hi,
                                            mobv_lo, ibvT, bias);
  k_wvcast<<<(HE * P_) / 1024, 256, 0, stream>>>(wv, wvb);
  k_w2p<<<dim3(NL / 64, HE / 64, B_), 256, 0, stream>>>(mobv, wv, bv, W2pT);
  k_scores<<<dim3(8192 / 64, NL / 64, B_), 256, 0, stream>>>(
      u, mobv_hi, mobv_lo, pb, bias, mask, attn);
  k_softmax<<<B_ * H_ * NT, 256, 0, stream>>>(attn);
  k_out<<<dim3(NT / 32, BH), 256, 0, stream>>>(attn, ibvT, W2pT, u, wvb, out);
}

// Round 3
// 653.149 us; speedup vs baseline: 3.3475x; 1.7592x over previous
//
#include <hip/hip_runtime.h>
#include <cstdint>
#include <cstddef>
#include <cmath>

#define B_  4
#define H_  16
#define NT  512
#define NL  512
#define E_  64
#define P_  1024
#define HE  1024
#define BH  64

typedef __attribute__((ext_vector_type(8))) short short8;
typedef __attribute__((ext_vector_type(4))) float f32x4;
typedef unsigned short u16;

#define MFMA(a, b, c) __builtin_amdgcn_mfma_f32_16x16x32_bf16(a, b, c, 0, 0, 0)

static __device__ inline u16 f2bf_rne(float f) {
  unsigned u = __float_as_uint(f);
  unsigned r = u + 0x7FFFu + ((u >> 16) & 1u);
  return (u16)(r >> 16);
}

// async 16B global -> LDS (wave-uniform LDS base + lane*16)
static __device__ inline void gl_lds16(const void* g, void* l) {
  __builtin_amdgcn_global_load_lds(
      (const __attribute__((address_space(1))) void*)g,
      (__attribute__((address_space(3))) void*)l, 16, 0, 0);
}

// ---------------------------------------------------------------------------
// Kernel A: per (b,n):
//   inv = 1/(exp(logvar)+8); mobv hi/lo bf16 split;
//   ibvT[b][p][n] = bf16(inv)  (transposed for MFMA B-fragments);
//   bias = log(pi) - 0.5*sum(mu^2*inv) - 0.5*sum(log(bv))
// ---------------------------------------------------------------------------
__global__ __launch_bounds__(256) void k_precompute(
    const float* __restrict__ mu, const float* __restrict__ logvar,
    const float* __restrict__ pi, u16* __restrict__ mobv_hi,
    u16* __restrict__ mobv_lo, u16* __restrict__ ibvT,
    float* __restrict__ bias) {
  const int bn = blockIdx.x;          // 0 .. B_*NL-1
  const int b = bn >> 9, n = bn & 511;
  const int t = threadIdx.x;
  const size_t base = (size_t)bn * P_;
  float t2 = 0.f, t3 = 0.f;
#pragma unroll
  for (int i = 0; i < P_ / 256; ++i) {
    const int p = t + i * 256;
    const float lv  = logvar[base + p];
    const float v   = expf(lv);
    const float bv  = v + 8.0f;
    const float inv = 1.0f / bv;
    const float m   = mu[base + p];
    const float x   = m * inv;
    const unsigned bits = __float_as_uint(x);
    mobv_hi[base + p] = (u16)(bits >> 16);
    const float r = x - __uint_as_float(bits & 0xFFFF0000u);
    mobv_lo[base + p] = (u16)(__float_as_uint(r) >> 16);
    ibvT[((size_t)b * P_ + p) * NL + n] = f2bf_rne(inv);
    t2 += m * x;
    t3 += logf(bv);
  }
  __shared__ float r2[256];
  __shared__ float r3[256];
  r2[t] = t2; r3[t] = t3;
  __syncthreads();
  for (int s = 128; s > 0; s >>= 1) {
    if (t < s) { r2[t] += r2[t + s]; r3[t] += r3[t + s]; }
    __syncthreads();
  }
  if (t == 0) {
    const float pv = pi[bn];
    float bb;
    if (pv <= 0.f) bb = -INFINITY;
    else bb = logf(fmaxf(pv, 1.17549435e-38f)) - 0.5f * r2[0] - 0.5f * r3[0];
    bias[bn] = bb;
  }
}

// ---------------------------------------------------------------------------
// wv fp32 -> bf16 copy
// ---------------------------------------------------------------------------
__global__ __launch_bounds__(256) void k_wvcast(const float* __restrict__ wv,
                                                u16* __restrict__ wvb) {
  const int i = (blockIdx.x * 256 + threadIdx.x) * 4;
  const float4 f = *(const float4*)&wv[i];
  wvb[i + 0] = f2bf_rne(f.x);
  wvb[i + 1] = f2bf_rne(f.y);
  wvb[i + 2] = f2bf_rne(f.z);
  wvb[i + 3] = f2bf_rne(f.w);
}

// ---------------------------------------------------------------------------
// Kernel W (MFMA): W2pT[b][he][n] = bf16(8*sum_p mobv[n][p]*wv[he][p] + bv[he][n])
// M=512(n) x N=1024(he) x K=1024. Tile 64x128xBK32; 4 waves 2x2 (wave 32x64).
// A = mobv hi/lo bf16, B = wvb bf16 (hi only; 2-term split).
// ---------------------------------------------------------------------------
__global__ __launch_bounds__(256) void k_w2p(
    const u16* __restrict__ mobv_hi, const u16* __restrict__ mobv_lo,
    const u16* __restrict__ wvb, const float* __restrict__ bv_,
    u16* __restrict__ W2pT) {
  const int b    = blockIdx.z;
  const int row0 = blockIdx.x * 64;    // n
  const int col0 = blockIdx.y * 128;   // he
  const int t = threadIdx.x;
  const int wave = t >> 6, lane = t & 63;
  const int l16 = lane & 15, sel = lane >> 4;
  const int mrow = (wave >> 1) * 32, ncol = (wave & 1) * 64;

  __shared__ u16 Ah[64 * 32];    // 4KB
  __shared__ u16 Al[64 * 32];    // 4KB
  __shared__ u16 Bs[128 * 32];   // 8KB

  const u16* Abh = mobv_hi + ((size_t)b * NL + row0) * P_;
  const u16* Abl = mobv_lo + ((size_t)b * NL + row0) * P_;
  const u16* Bb  = wvb + (size_t)col0 * P_;

  f32x4 acc[2][4];
#pragma unroll
  for (int i = 0; i < 2; ++i)
#pragma unroll
    for (int j = 0; j < 4; ++j) acc[i][j] = (f32x4){0.f, 0.f, 0.f, 0.f};

  for (int k0 = 0; k0 < P_; k0 += 32) {
    {  // A tiles: 256 chunks each
      const int c = t;
      const int row = c >> 2, k8 = (c & 3) ^ ((row >> 1) & 3);
      gl_lds16(Abh + (size_t)row * P_ + k0 + k8 * 8, &Ah[wave * 64 * 8]);
      gl_lds16(Abl + (size_t)row * P_ + k0 + k8 * 8, &Al[wave * 64 * 8]);
    }
#pragma unroll
    for (int i = 0; i < 2; ++i) {  // B tile: 512 chunks
      const int c = t + i * 256;
      const int row = c >> 2, k8 = (c & 3) ^ ((row >> 1) & 3);
      gl_lds16(Bb + (size_t)row * P_ + k0 + k8 * 8,
               &Bs[(i * 256 + wave * 64) * 8]);
    }
    __syncthreads();
    short8 ah[2], al[2], bf[4];
#pragma unroll
    for (int mt = 0; mt < 2; ++mt) {
      const int r = mrow + mt * 16 + l16;
      const int ch = sel ^ ((r >> 1) & 3);
      ah[mt] = *(const short8*)&Ah[r * 32 + ch * 8];
      al[mt] = *(const short8*)&Al[r * 32 + ch * 8];
    }
#pragma unroll
    for (int nt = 0; nt < 4; ++nt) {
      const int r = ncol + nt * 16 + l16;
      const int ch = sel ^ ((r >> 1) & 3);
      bf[nt] = *(const short8*)&Bs[r * 32 + ch * 8];
    }
#pragma unroll
    for (int mt = 0; mt < 2; ++mt)
#pragma unroll
      for (int nt = 0; nt < 4; ++nt) {
        acc[mt][nt] = MFMA(ah[mt], bf[nt], acc[mt][nt]);
        acc[mt][nt] = MFMA(al[mt], bf[nt], acc[mt][nt]);
      }
    __syncthreads();
  }
#pragma unroll
  for (int mt = 0; mt < 2; ++mt) {
    const int nbase = row0 + mrow + mt * 16 + sel * 4;
#pragma unroll
    for (int nt = 0; nt < 4; ++nt) {
      const int he = col0 + ncol + nt * 16 + l16;
      const float4 bvv = *(const float4*)&bv_[(size_t)he * NL + nbase];
      ushort4 o;
      o.x = f2bf_rne(8.0f * acc[mt][nt][0] + bvv.x);
      o.y = f2bf_rne(8.0f * acc[mt][nt][1] + bvv.y);
      o.z = f2bf_rne(8.0f * acc[mt][nt][2] + bvv.z);
      o.w = f2bf_rne(8.0f * acc[mt][nt][3] + bvv.w);
      *(ushort4*)&W2pT[((size_t)b * HE + he) * NL + nbase] = o;
    }
  }
}

// ---------------------------------------------------------------------------
// Kernel S (MFMA, m97-style): scores = U @ mobv^T, 3-term split-bf16.
// 128x128xBK32 tile, 4 waves 2x2 (wave 64x64, 16 acc tiles).
// A = U fp32 staged via global_load_lds, hi/lo split in-register.
// B = mobv_hi/lo bf16 staged via global_load_lds.
// XOR chunk swizzle breaks LDS bank conflicts (padding is illegal w/ load_lds).
// ---------------------------------------------------------------------------
__global__ __launch_bounds__(256) void k_scores(
    const float* __restrict__ U, const u16* __restrict__ mobv_hi,
    const u16* __restrict__ mobv_lo, const float* __restrict__ pb,
    const float* __restrict__ bias, const uint8_t* __restrict__ mask,
    float* __restrict__ attn) {
  const int b    = blockIdx.z;
  const int row0 = blockIdx.x * 128;  // gr within b
  const int col0 = blockIdx.y * 128;  // n
  const int t = threadIdx.x;
  const int wave = t >> 6, lane = t & 63;
  const int l16 = lane & 15, sel = lane >> 4;
  const int mrow = (wave >> 1) * 64, ncol = (wave & 1) * 64;

  __shared__ float Af[128 * 32];  // 16KB
  __shared__ u16   Bh[128 * 32];  // 8KB
  __shared__ u16   Bl[128 * 32];  // 8KB

  const float* Ab  = U + ((size_t)b * 8192 + row0) * P_;
  const u16*   Bbh = mobv_hi + ((size_t)b * NL + col0) * P_;
  const u16*   Bbl = mobv_lo + ((size_t)b * NL + col0) * P_;

  f32x4 acc[4][4];
#pragma unroll
  for (int i = 0; i < 4; ++i)
#pragma unroll
    for (int j = 0; j < 4; ++j) acc[i][j] = (f32x4){0.f, 0.f, 0.f, 0.f};

  for (int k0 = 0; k0 < P_; k0 += 32) {
    // stage A fp32: 1024 chunks of 16B
#pragma unroll
    for (int i = 0; i < 4; ++i) {
      const int c = t + i * 256;
      const int row = c >> 3, k4 = (c & 7) ^ (row & 7);
      gl_lds16(Ab + (size_t)row * P_ + k0 + k4 * 4,
               &Af[(i * 256 + wave * 64) * 4]);
    }
    // stage B hi/lo bf16: 512 chunks each
#pragma unroll
    for (int i = 0; i < 2; ++i) {
      const int c = t + i * 256;
      const int row = c >> 2, k8 = (c & 3) ^ ((row >> 1) & 3);
      gl_lds16(Bbh + (size_t)row * P_ + k0 + k8 * 8,
               &Bh[(i * 256 + wave * 64) * 8]);
      gl_lds16(Bbl + (size_t)row * P_ + k0 + k8 * 8,
               &Bl[(i * 256 + wave * 64) * 8]);
    }
    __syncthreads();

    short8 ah[4], al[4], bh[4], bl[4];
#pragma unroll
    for (int mt = 0; mt < 4; ++mt) {
      const int r = mrow + mt * 16 + l16;
      const int c0 = (sel * 2) ^ (r & 7);
      const int c1 = (sel * 2 + 1) ^ (r & 7);
      const float4 f0 = *(const float4*)&Af[r * 32 + c0 * 4];
      const float4 f1 = *(const float4*)&Af[r * 32 + c1 * 4];
      const float fv[8] = {f0.x, f0.y, f0.z, f0.w, f1.x, f1.y, f1.z, f1.w};
#pragma unroll
      for (int j = 0; j < 8; ++j) {
        const unsigned bits = __float_as_uint(fv[j]);
        ah[mt][j] = (short)(bits >> 16);
        const float rr = fv[j] - __uint_as_float(bits & 0xFFFF0000u);
        al[mt][j] = (short)(__float_as_uint(rr) >> 16);
      }
    }
#pragma unroll
    for (int nt = 0; nt < 4; ++nt) {
      const int r = ncol + nt * 16 + l16;
      const int ch = sel ^ ((r >> 1) & 3);
      bh[nt] = *(const short8*)&Bh[r * 32 + ch * 8];
      bl[nt] = *(const short8*)&Bl[r * 32 + ch * 8];
    }
#pragma unroll
    for (int mt = 0; mt < 4; ++mt)
#pragma unroll
      for (int nt = 0; nt < 4; ++nt) {
        acc[mt][nt] = MFMA(ah[mt], bh[nt], acc[mt][nt]);
        acc[mt][nt] = MFMA(ah[mt], bl[nt], acc[mt][nt]);
        acc[mt][nt] = MFMA(al[mt], bh[nt], acc[mt][nt]);
      }
    __syncthreads();
  }

  const int bh_ = b * H_ + (row0 >> 9);
  float pbv[4][4];
#pragma unroll
  for (int mt = 0; mt < 4; ++mt)
#pragma unroll
    for (int r = 0; r < 4; ++r)
      pbv[mt][r] = pb[(size_t)b * 8192 + row0 + mrow + mt * 16 + sel * 4 + r];
#pragma unroll
  for (int nt = 0; nt < 4; ++nt) {
    const int n = col0 + ncol + nt * 16 + l16;
    const float bcol = bias[b * NL + n];
    const bool mk = mask[(size_t)bh_ * NL + n] != 0;
#pragma unroll
    for (int mt = 0; mt < 4; ++mt) {
#pragma unroll
      for (int r = 0; r < 4; ++r) {
        const int row = row0 + mrow + mt * 16 + sel * 4 + r;
        float s = acc[mt][nt][r] + pbv[mt][r] + bcol;
        if (mk) s = -INFINITY;
        attn[((size_t)b * 8192 + row) * NL + n] = s;
      }
    }
  }
}

// ---------------------------------------------------------------------------
// Kernel SM: softmax over last dim (512), in place. One block per row.
// ---------------------------------------------------------------------------
__global__ __launch_bounds__(256) void k_softmax(float* __restrict__ attn) {
  const size_t r = blockIdx.x;
  float* row = attn + r * NL;
  const int t = threadIdx.x;
  float2 v = ((float2*)row)[t];
  __shared__ float red[256];
  red[t] = fmaxf(v.x, v.y);
  __syncthreads();
  for (int s = 128; s > 0; s >>= 1) {
    if (t < s) red[t] = fmaxf(red[t], red[t + s]);
    __syncthreads();
  }
  const float M = red[0];
  __syncthreads();
  const float e0 = expf(v.x - M);
  const float e1 = expf(v.y - M);
  red[t] = e0 + e1;
  __syncthreads();
  for (int s = 128; s > 0; s >>= 1) {
    if (t < s) red[t] += red[t + s];
    __syncthreads();
  }
  const float inv = 1.0f / red[0];
  float2 o; o.x = e0 * inv; o.y = e1 * inv;
  ((float2*)row)[t] = o;
}

// ---------------------------------------------------------------------------
// Kernel O (MFMA): fused output. Block: one bh, 32 rows of Nt; 4 waves.
// ---------------------------------------------------------------------------
__global__ __launch_bounds__(256) void k_out(
    const float* __restrict__ attn, const u16* __restrict__ ibvT,
    const u16* __restrict__ W2pT, const float* __restrict__ U,
    const u16* __restrict__ wvb, float* __restrict__ out) {
  const int bh = blockIdx.y;
  const int b = bh >> 4, h = bh & 15;
  const int row0g = bh * NT + blockIdx.x * 32;
  const int t = threadIdx.x;
  const int wave = t >> 6, lane = t & 63;
  const int l16 = lane & 15, sel = lane >> 4;
  const int mh = (wave & 1) * 16;
  const int eh = (wave >> 1) * 32;
  const int ph = (wave >> 1) * 32;

  __shared__ u16 As[32][520];
  __shared__ u16 opS[32][72];

#pragma unroll
  for (int i = 0; i < 16; ++i) {
    const int idx = t + i * 256;
    const int row = idx >> 7;
    const int c4 = (idx & 127) * 4;
    const float4 f = *(const float4*)&attn[(size_t)(row0g + row) * NL + c4];
    As[row][c4 + 0] = f2bf_rne(f.x);
    As[row][c4 + 1] = f2bf_rne(f.y);
    As[row][c4 + 2] = f2bf_rne(f.z);
    As[row][c4 + 3] = f2bf_rne(f.w);
  }
  __syncthreads();

  f32x4 acc0 = (f32x4){0.f, 0.f, 0.f, 0.f};
  f32x4 acc1 = (f32x4){0.f, 0.f, 0.f, 0.f};

  // term2: acc += A @ W2pT^T   (k = n, 512)
#pragma unroll 4
  for (int ks = 0; ks < 16; ++ks) {
    const short8 a = *(const short8*)&As[mh + l16][ks * 32 + sel * 8];
    const int he0 = h * 64 + eh + l16;
    const short8 b0 =
        *(const short8*)&W2pT[((size_t)b * HE + he0) * NL + ks * 32 + sel * 8];
    acc0 = MFMA(a, b0, acc0);
    const short8 b1 = *(const short8*)&W2pT[((size_t)b * HE + he0 + 16) * NL +
                                            ks * 32 + sel * 8];
    acc1 = MFMA(a, b1, acc1);
  }

  for (int c = 0; c < 16; ++c) {
    const int p0 = c * 64;
    f32x4 s0 = (f32x4){0.f, 0.f, 0.f, 0.f};
    f32x4 s1 = (f32x4){0.f, 0.f, 0.f, 0.f};
#pragma unroll 4
    for (int ks = 0; ks < 16; ++ks) {
      const short8 a = *(const short8*)&As[mh + l16][ks * 32 + sel * 8];
      const int pc = p0 + ph + l16;
      const short8 b0 =
          *(const short8*)&ibvT[((size_t)b * P_ + pc) * NL + ks * 32 + sel * 8];
      s0 = MFMA(a, b0, s0);
      const short8 b1 = *(const short8*)&ibvT[((size_t)b * P_ + pc + 16) * NL +
                                              ks * 32 + sel * 8];
      s1 = MFMA(a, b1, s1);
    }
#pragma unroll
    for (int r = 0; r < 4; ++r) {
      const int row = mh + sel * 4 + r;
      const float u0 = U[(size_t)(row0g + row) * P_ + p0 + ph + l16];
      const float u1 = U[(size_t)(row0g + row) * P_ + p0 + ph + 16 + l16];
      opS[row][ph + l16]      = f2bf_rne((1.0f - 8.0f * s0[r]) * u0);
      opS[row][ph + 16 + l16] = f2bf_rne((1.0f - 8.0f * s1[r]) * u1);
    }
    __syncthreads();
#pragma unroll
    for (int ks = 0; ks < 2; ++ks) {
      const short8 a = *(const short8*)&opS[mh + l16][ks * 32 + sel * 8];
      const int he0 = h * 64 + eh + l16;
      const short8 b0 =
          *(const short8*)&wvb[(size_t)he0 * P_ + p0 + ks * 32 + sel * 8];
      acc0 = MFMA(a, b0, acc0);
      const short8 b1 = *(const short8*)&wvb[(size_t)(he0 + 16) * P_ + p0 +
                                             ks * 32 + sel * 8];
      acc1 = MFMA(a, b1, acc1);
    }
    __syncthreads();
  }
#pragma unroll
  for (int r = 0; r < 4; ++r) {
    const int row = mh + sel * 4 + r;
    out[(size_t)(row0g + row) * E_ + eh + l16]      = acc0[r];
    out[(size_t)(row0g + row) * E_ + eh + 16 + l16] = acc1[r];
  }
}

// ---------------------------------------------------------------------------
extern "C" void kernel_launch(void* const* d_in, const int* in_sizes, int n_in,
                              void* d_out, int out_size, void* d_ws, size_t ws_size,
                              hipStream_t stream) {
  const float*   u    = (const float*)d_in[0];   // [B,H,Nt,P]
  const float*   pb   = (const float*)d_in[1];   // [B,H,Nt,1]
  const float*   mu   = (const float*)d_in[2];   // [B,Nl,P]
  const float*   logv = (const float*)d_in[3];   // [B,Nl,P]
  const float*   pi   = (const float*)d_in[4];   // [B,Nl,1]
  const float*   wv   = (const float*)d_in[5];   // [H,E,P]
  const float*   bv   = (const float*)d_in[6];   // [H,E,Nl]
  const uint8_t* mask = (const uint8_t*)d_in[7]; // [B*H,1,Nl] bool

  float* out  = (float*)d_out;                      // [B*H,Nt,E]
  float* attn = out + (size_t)BH * NT * E_;         // [B*H,Nt,Nl]

  u16*   mobv_hi = (u16*)d_ws;                              // 4 MB
  u16*   mobv_lo = mobv_hi + (size_t)B_ * NL * P_;          // 4 MB
  u16*   ibvT    = mobv_lo + (size_t)B_ * NL * P_;          // [b][p][n] 4 MB
  u16*   W2pT    = ibvT + (size_t)B_ * P_ * NL;             // [b][he][n] 4 MB
  u16*   wvb     = W2pT + (size_t)B_ * HE * NL;             // [he][p] 2 MB
  float* bias    = (float*)(wvb + (size_t)HE * P_);         // B*NL

  k_precompute<<<B_ * NL, 256, 0, stream>>>(mu, logv, pi, mobv_hi, mobv_lo,
                                            ibvT, bias);
  k_wvcast<<<(HE * P_) / 1024, 256, 0, stream>>>(wv, wvb);
  k_w2p<<<dim3(NL / 64, HE / 128, B_), 256, 0, stream>>>(mobv_hi, mobv_lo, wvb,
                                                         bv, W2pT);
  k_scores<<<dim3(8192 / 128, NL / 128, B_), 256, 0, stream>>>(
      u, mobv_hi, mobv_lo, pb, bias, mask, attn);
  k_softmax<<<B_ * H_ * NT, 256, 0, stream>>>(attn);
  k_out<<<dim3(NT / 32, BH), 256, 0, stream>>>(attn, ibvT, W2pT, u, wvb, out);
}